// Round 1
// baseline (121.479 us; speedup 1.0000x reference)
//
#include <hip/hip_runtime.h>

// Problem constants (from reference setup_inputs)
#define B_  4
#define O_  32
#define C_  32
#define H_  32
#define W_  32
#define P_  5
#define T_  288      // C*3*3
#define EPSF 1e-6f

// Table layout per (o,t): 16 floats
//   e[0..3]  = inv_k  = 1/(p[k+1]-p[k]+EPS)
//   e[4..7]  = -p[k]*inv_k
//   e[8..11] = v[k+1]-v[k]
//   e[12]    = v[0]
//   e[13..15] pad

__global__ __launch_bounds__(256) void prep_tables(
    const float* __restrict__ pos, const float* __restrict__ val,
    float* __restrict__ tab)
{
    int id = blockIdx.x * 256 + threadIdx.x;
    if (id >= O_ * T_) return;

    const float* pp = pos + id * P_;
    const float* vv = val + id * P_;
    float p0 = pp[0], p1 = pp[1], p2 = pp[2], p3 = pp[3], p4 = pp[4];
    float v0 = vv[0], v1 = vv[1], v2 = vv[2], v3 = vv[3], v4 = vv[4];

    // 9-CE sorting network for 5 elements, values carried along.
#define CSWAP(a, b, va, vb)                         \
    {                                               \
        float _pa = fminf(a, b), _pb = fmaxf(a, b); \
        bool _sw = (a > b);                         \
        float _va = _sw ? vb : va;                  \
        float _vb = _sw ? va : vb;                  \
        a = _pa; b = _pb; va = _va; vb = _vb;       \
    }
    CSWAP(p0, p1, v0, v1);
    CSWAP(p3, p4, v3, v4);
    CSWAP(p2, p4, v2, v4);
    CSWAP(p2, p3, v2, v3);
    CSWAP(p1, p4, v1, v4);
    CSWAP(p0, p3, v0, v3);
    CSWAP(p0, p2, v0, v2);
    CSWAP(p1, p3, v1, v3);
    CSWAP(p1, p2, v1, v2);
#undef CSWAP

    float inv0 = 1.0f / (p1 - p0 + EPSF);
    float inv1 = 1.0f / (p2 - p1 + EPSF);
    float inv2 = 1.0f / (p3 - p2 + EPSF);
    float inv3 = 1.0f / (p4 - p3 + EPSF);

    float* e = tab + id * 16;
    e[0]  = inv0;        e[1]  = inv1;        e[2]  = inv2;        e[3]  = inv3;
    e[4]  = -p0 * inv0;  e[5]  = -p1 * inv1;  e[6]  = -p2 * inv2;  e[7]  = -p3 * inv3;
    e[8]  = v1 - v0;     e[9]  = v2 - v1;     e[10] = v3 - v2;     e[11] = v4 - v3;
    e[12] = v0;          e[13] = 0.f;         e[14] = 0.f;         e[15] = 0.f;
}

// One block per (b, o, 8-row strip). 256 threads, 1 output pixel each.
// x slab (all 32 channels, 10 rows with halo, 34 cols with halo) in LDS.
#define TILE_ROWS 8
#define LDS_R 10
#define LDS_C 34
#define XS_PER_CH (LDS_R * LDS_C)   // 340

__global__ __launch_bounds__(256) void pw_conv(
    const float* __restrict__ x, const float* __restrict__ tab,
    float* __restrict__ out)
{
    __shared__ float xs[C_ * XS_PER_CH];   // 43520 B

    const int b  = blockIdx.z;
    const int o  = blockIdx.y;
    const int r0 = blockIdx.x * TILE_ROWS;
    const int tid = threadIdx.x;

    // ---- stage x[b, :, r0-1 .. r0+8, -1..32] into LDS (zero-padded) ----
    const float* xb = x + b * (C_ * H_ * W_);
    for (int idx = tid; idx < C_ * XS_PER_CH; idx += 256) {
        int c   = idx / XS_PER_CH;
        int rem = idx - c * XS_PER_CH;
        int r   = rem / LDS_C;
        int col = rem - r * LDS_C;
        int gr = r0 + r - 1;
        int gc = col - 1;
        float v = 0.f;
        if ((unsigned)gr < (unsigned)H_ && (unsigned)gc < (unsigned)W_)
            v = xb[c * (H_ * W_) + gr * W_ + gc];
        xs[idx] = v;
    }
    __syncthreads();

    const int lr = tid >> 5;     // 0..7  local row
    const int lc = tid & 31;     // 0..31 local col
    const float* tb = tab + o * (T_ * 16);

    float acc = 0.f;
    for (int c = 0; c < C_; ++c) {
        const float* xrow = xs + c * XS_PER_CH + lr * LDS_C + lc;
        const float* ec = tb + c * 9 * 16;
#pragma unroll
        for (int ij = 0; ij < 9; ++ij) {
            const int i = ij / 3, j = ij % 3;
            float xv = xrow[i * LDS_C + j];     // ds_read_b32, imm offset
            const float* e = ec + ij * 16;
            float r = e[12];
#pragma unroll
            for (int k = 0; k < 4; ++k) {
                float tt = fmaf(xv, e[k], e[4 + k]);
                tt = fminf(fmaxf(tt, 0.f), 1.f);
                r = fmaf(tt, e[8 + k], r);
            }
            acc += r;
        }
    }

    out[(b * O_ + o) * (H_ * W_) + (r0 + lr) * W_ + lc] = acc;
}

extern "C" void kernel_launch(void* const* d_in, const int* in_sizes, int n_in,
                              void* d_out, int out_size, void* d_ws, size_t ws_size,
                              hipStream_t stream)
{
    const float* x   = (const float*)d_in[0];
    const float* pos = (const float*)d_in[1];
    const float* val = (const float*)d_in[2];
    float* tab = (float*)d_ws;              // needs 32*288*16*4 = 589824 B

    // Phase 1: sort breakpoints + precompute segment coefficients.
    prep_tables<<<(O_ * T_ + 255) / 256, 256, 0, stream>>>(pos, val, tab);

    // Phase 2: evaluate. grid = (row strips, O, B)
    dim3 grid(H_ / TILE_ROWS, O_, B_);
    pw_conv<<<grid, 256, 0, stream>>>(x, tab, (float*)d_out);
}

// Round 4
// 90.946 us; speedup vs baseline: 1.3357x; 1.3357x over previous
//
#include <hip/hip_runtime.h>

// Problem constants (from reference setup_inputs)
#define B_  4
#define O_  32
#define C_  32
#define H_  32
#define W_  32
#define P_  5
#define T_  288      // C*3*3
#define EPSF 1e-6f

#define NCH 4                 // channels per block
#define CG  (C_ / NCH)        // 8 channel-groups

// Table layout per (o,t): 16 floats
//   e[0..3]  = inv_k  = 1/(p[k+1]-p[k]+EPS)
//   e[4..7]  = -p[k]*inv_k
//   e[8..11] = v[k+1]-v[k]
//   e[12]    = v[0]

__global__ __launch_bounds__(256) void zero_out(float* __restrict__ out, int n)
{
    int i = blockIdx.x * 256 + threadIdx.x;
    if (i < n) out[i] = 0.f;
}

__global__ __launch_bounds__(256) void prep_tables(
    const float* __restrict__ pos, const float* __restrict__ val,
    float* __restrict__ tab)
{
    int id = blockIdx.x * 256 + threadIdx.x;
    if (id >= O_ * T_) return;

    const float* pp = pos + id * P_;
    const float* vv = val + id * P_;
    float p0 = pp[0], p1 = pp[1], p2 = pp[2], p3 = pp[3], p4 = pp[4];
    float v0 = vv[0], v1 = vv[1], v2 = vv[2], v3 = vv[3], v4 = vv[4];

    // 9-CE sorting network for 5 elements, values carried along.
#define CSWAP(a, b, va, vb)                         \
    {                                               \
        float _pa = fminf(a, b), _pb = fmaxf(a, b); \
        bool _sw = (a > b);                         \
        float _va = _sw ? vb : va;                  \
        float _vb = _sw ? va : vb;                  \
        a = _pa; b = _pb; va = _va; vb = _vb;       \
    }
    CSWAP(p0, p1, v0, v1);
    CSWAP(p3, p4, v3, v4);
    CSWAP(p2, p4, v2, v4);
    CSWAP(p2, p3, v2, v3);
    CSWAP(p1, p4, v1, v4);
    CSWAP(p0, p3, v0, v3);
    CSWAP(p0, p2, v0, v2);
    CSWAP(p1, p3, v1, v3);
    CSWAP(p1, p2, v1, v2);
#undef CSWAP

    float inv0 = 1.0f / (p1 - p0 + EPSF);
    float inv1 = 1.0f / (p2 - p1 + EPSF);
    float inv2 = 1.0f / (p3 - p2 + EPSF);
    float inv3 = 1.0f / (p4 - p3 + EPSF);

    float* e = tab + id * 16;
    e[0]  = inv0;        e[1]  = inv1;        e[2]  = inv2;        e[3]  = inv3;
    e[4]  = -p0 * inv0;  e[5]  = -p1 * inv1;  e[6]  = -p2 * inv2;  e[7]  = -p3 * inv3;
    e[8]  = v1 - v0;     e[9]  = v2 - v1;     e[10] = v3 - v2;     e[11] = v4 - v3;
    e[12] = v0;          e[13] = 0.f;         e[14] = 0.f;         e[15] = 0.f;
}

// Block = (channel-group cg, o, b); 256 threads; full 32x32 image.
// Thread owns 4 consecutive cols of one row: r = tid>>3, c4 = (tid&7)*4.
// x slab: NCH channels, 34 rows halo, 34 cols halo, row stride 35 (bank pad).
#define XROW 34
#define XSTR 35
#define XS_PER_CH (XROW * XSTR)   // 1190

__global__ __launch_bounds__(256, 4) void pw_conv(
    const float* __restrict__ x, const float* __restrict__ tab,
    float* __restrict__ out)
{
    __shared__ float xs[NCH * XS_PER_CH];   // 19040 B

    const int cg = blockIdx.x;      // 0..CG-1
    const int o  = blockIdx.y;
    const int b  = blockIdx.z;
    const int tid = threadIdx.x;
    const int c0 = cg * NCH;

    // ---- stage x[b, c0..c0+3, -1..32, -1..32] into LDS (zero-padded) ----
    const float* xb = x + (b * C_ + c0) * (H_ * W_);
    for (int idx = tid; idx < NCH * XROW * XROW; idx += 256) {
        int ch  = idx / (XROW * XROW);
        int rem = idx - ch * (XROW * XROW);
        int r   = rem / XROW;             // 0..33 padded row
        int col = rem - r * XROW;         // 0..33 padded col
        int gr = r - 1, gc = col - 1;
        float v = 0.f;
        if ((unsigned)gr < (unsigned)H_ && (unsigned)gc < (unsigned)W_)
            v = xb[ch * (H_ * W_) + gr * W_ + gc];
        xs[ch * XS_PER_CH + r * XSTR + col] = v;
    }
    __syncthreads();

    const int r  = tid >> 3;          // 0..31 output row
    const int c4 = (tid & 7) * 4;     // 0,4,...,28 output col base
    const float* tb = tab + (o * T_ + c0 * 9) * 16;

    float acc0 = 0.f, acc1 = 0.f, acc2 = 0.f, acc3 = 0.f;

    for (int ch = 0; ch < NCH; ++ch) {
        // x window: padded rows r..r+2, padded cols c4..c4+5  (18 regs)
        float xr[3][6];
#pragma unroll
        for (int i = 0; i < 3; ++i)
#pragma unroll
            for (int j = 0; j < 6; ++j)
                xr[i][j] = xs[ch * XS_PER_CH + (r + i) * XSTR + c4 + j];

        const float* ec = tb + ch * 9 * 16;
#pragma unroll
        for (int ij = 0; ij < 9; ++ij) {
            const int i = ij / 3, j = ij % 3;
            const float* e = ec + ij * 16;
            float i0 = e[0], i1 = e[1], i2 = e[2], i3 = e[3];
            float f0 = e[4], f1 = e[5], f2 = e[6], f3 = e[7];
            float d0 = e[8], d1 = e[9], d2 = e[10], d3 = e[11];
            float v0 = e[12];

#define EVAL(ACC, XV)                                                      \
            {                                                              \
                float _xv = (XV);                                          \
                ACC += v0;                                                 \
                float _t;                                                  \
                _t = fmaf(_xv, i0, f0);                                    \
                _t = fminf(fmaxf(_t, 0.f), 1.f); ACC = fmaf(_t, d0, ACC);  \
                _t = fmaf(_xv, i1, f1);                                    \
                _t = fminf(fmaxf(_t, 0.f), 1.f); ACC = fmaf(_t, d1, ACC);  \
                _t = fmaf(_xv, i2, f2);                                    \
                _t = fminf(fmaxf(_t, 0.f), 1.f); ACC = fmaf(_t, d2, ACC);  \
                _t = fmaf(_xv, i3, f3);                                    \
                _t = fminf(fmaxf(_t, 0.f), 1.f); ACC = fmaf(_t, d3, ACC);  \
            }
            EVAL(acc0, xr[i][j + 0]);
            EVAL(acc1, xr[i][j + 1]);
            EVAL(acc2, xr[i][j + 2]);
            EVAL(acc3, xr[i][j + 3]);
#undef EVAL
        }
    }

    float* op = out + (b * O_ + o) * (H_ * W_) + r * W_ + c4;
    __hip_atomic_fetch_add(op + 0, acc0, __ATOMIC_RELAXED, __HIP_MEMORY_SCOPE_AGENT);
    __hip_atomic_fetch_add(op + 1, acc1, __ATOMIC_RELAXED, __HIP_MEMORY_SCOPE_AGENT);
    __hip_atomic_fetch_add(op + 2, acc2, __ATOMIC_RELAXED, __HIP_MEMORY_SCOPE_AGENT);
    __hip_atomic_fetch_add(op + 3, acc3, __ATOMIC_RELAXED, __HIP_MEMORY_SCOPE_AGENT);
}

extern "C" void kernel_launch(void* const* d_in, const int* in_sizes, int n_in,
                              void* d_out, int out_size, void* d_ws, size_t ws_size,
                              hipStream_t stream)
{
    const float* x   = (const float*)d_in[0];
    const float* pos = (const float*)d_in[1];
    const float* val = (const float*)d_in[2];
    float* tab = (float*)d_ws;              // needs 32*288*16*4 = 589824 B

    // Output accumulated via atomics -> zero it first (d_out is poisoned 0xAA).
    zero_out<<<(out_size + 255) / 256, 256, 0, stream>>>((float*)d_out, out_size);

    // Phase 1: sort breakpoints + precompute segment coefficients.
    prep_tables<<<(O_ * T_ + 255) / 256, 256, 0, stream>>>(pos, val, tab);

    // Phase 2: evaluate. grid = (channel groups, O, B)
    dim3 grid(CG, O_, B_);
    pw_conv<<<grid, 256, 0, stream>>>(x, tab, (float*)d_out);
}